// Round 8
// baseline (306.728 us; speedup 1.0000x reference)
//
#include <hip/hip_runtime.h>

#define H 128
#define RREL 8
#define NJ 9        // 8 relations + root
#define CPAD 8      // ints per padded counter slot (32 B stride)

typedef short bf16x8 __attribute__((ext_vector_type(8)));
typedef float f32x4 __attribute__((ext_vector_type(4)));
typedef unsigned short u16x8 __attribute__((ext_vector_type(8)));

static __device__ __forceinline__ unsigned short f2bf(float f) {
    unsigned int u = __float_as_uint(f);
    unsigned int r = (u + 0x7fffu + ((u >> 16) & 1u)) >> 16;
    return (unsigned short)r;
}
static __device__ __forceinline__ float bf2f(unsigned short u) {
    return __uint_as_float(((unsigned int)u) << 16);
}

__global__ void zero_kernel(int* p, long n) {
    long i = (long)blockIdx.x * blockDim.x + threadIdx.x;
    long stride = (long)gridDim.x * blockDim.x;
    for (; i < n; i += stride) p[i] = 0;
}

// padded counters: cnt_pad[bin*CPAD]
__global__ void count_kernel(const int* __restrict__ ei, const int* __restrict__ et,
                             int* __restrict__ cnt_pad, int E) {
    int e = blockIdx.x * 256 + threadIdx.x;
    if (e >= E) return;
    int d = ei[E + e];
    int r = et[e];
    atomicAdd(&cnt_pad[(size_t)(d * RREL + r) << 3], 1);
}

__global__ void scan_block_kernel(const int* __restrict__ cnt_pad, int* __restrict__ rploc,
                                  int* __restrict__ bsum, int N) {
    __shared__ int s[256];
    int t = threadIdx.x;
    int d = blockIdx.x * 256 + t;
    int v = 0;
    if (d < N) {
#pragma unroll
        for (int r = 0; r < RREL; ++r) v += cnt_pad[(size_t)(d * RREL + r) << 3];
    }
    s[t] = v;
    __syncthreads();
#pragma unroll
    for (int off = 1; off < 256; off <<= 1) {
        int u = 0;
        if (t >= off) u = s[t - off];
        __syncthreads();
        s[t] += u;
        __syncthreads();
    }
    if (d < N) rploc[d] = s[t] - v;
    if (t == 255) bsum[blockIdx.x] = s[255];
}

__global__ void scan_top_kernel(const int* __restrict__ bsum, int* __restrict__ boff, int nb) {
    __shared__ int s[256];
    int t = threadIdx.x;
    int v = (t < nb) ? bsum[t] : 0;
    s[t] = v;
    __syncthreads();
#pragma unroll
    for (int off = 1; off < 256; off <<= 1) {
        int u = 0;
        if (t >= off) u = s[t - off];
        __syncthreads();
        s[t] += u;
        __syncthreads();
    }
    boff[t] = s[t] - v;
}

// rowptr[d] = dst-segment start; rowptr2[bin] = (d,r) sub-bin start; inv = 1/max(cnt,1)
// also zeroes cnt_pad slots so fill can reuse them as cursors
__global__ void finalize_kernel(int* __restrict__ cnt_pad, const int* __restrict__ rploc,
                                const int* __restrict__ boff, int* __restrict__ rowptr,
                                int* __restrict__ rowptr2, float* __restrict__ inv, int N) {
    int d = blockIdx.x * 256 + threadIdx.x;
    if (d >= N) return;
    int rp = rploc[d] + boff[d >> 8];
    rowptr[d] = rp;
    int run = rp;
#pragma unroll
    for (int r = 0; r < RREL; ++r) {
        int bin = d * RREL + r;
        int c = cnt_pad[(size_t)bin << 3];
        cnt_pad[(size_t)bin << 3] = 0;
        rowptr2[bin] = run;
        inv[bin] = 1.0f / (float)max(c, 1);
        run += c;
    }
    if (d == N - 1) rowptr[N] = run;
}

// packed[pos] = src | (rel<<20); positions ordered by (dst, rel); cnt_pad reused as cursor
__global__ void fill_kernel(const int* __restrict__ ei, const int* __restrict__ et,
                            int* __restrict__ cnt_pad, const int* __restrict__ rowptr2,
                            int* __restrict__ packed, int E) {
    int e = blockIdx.x * 256 + threadIdx.x;
    if (e >= E) return;
    int d = ei[E + e];
    int r = et[e];
    int bin = d * RREL + r;
    int pos = rowptr2[bin] + atomicAdd(&cnt_pad[(size_t)bin << 3], 1);
    packed[pos] = ei[e] | (r << 20);
}

__global__ void tobf_kernel(const float* __restrict__ x, unsigned short* __restrict__ xb, long n) {
    long i = (long)blockIdx.x * blockDim.x + threadIdx.x;
    long stride = (long)gridDim.x * blockDim.x;
    for (; i < n; i += stride) xb[i] = f2bf(x[i]);
}

// WTa1[j][f][k] = W1[j][k][f] / root1[k][f]   (normal K)
// WTa2[j][f][k'] = W2[j][orig(k')][f] / root2[orig(k')][f]   (orig(k')=(k'&7)*16+(k'>>3))
// biasP[0][c'] = b1[orig(c')], biasP[1][c'] = b2[orig(c')]
__global__ void wcat_kernel(const float* __restrict__ W1, const float* __restrict__ r1,
                            const float* __restrict__ W2, const float* __restrict__ r2,
                            const float* __restrict__ b1, const float* __restrict__ b2,
                            unsigned short* __restrict__ WTa1, unsigned short* __restrict__ WTa2,
                            float* __restrict__ biasP) {
    int id = blockIdx.x * 256 + threadIdx.x;
    const int per = NJ * H * H;
    if (id < per) {
        int j = id / (H * H);
        int fk = id - j * (H * H);
        int f = fk >> 7, k = fk & 127;
        float v = (j < RREL) ? W1[((size_t)j * H + k) * H + f] : r1[(size_t)k * H + f];
        WTa1[id] = f2bf(v);
        int ko = (k & 7) * 16 + (k >> 3);
        float v2 = (j < RREL) ? W2[((size_t)j * H + ko) * H + f] : r2[(size_t)ko * H + f];
        WTa2[id] = f2bf(v2);
    } else if (id < per + 2 * H) {
        int c = id - per;
        int cp = c & 127;
        int co = (cp & 7) * 16 + (cp >> 3);
        biasP[c] = (c < H) ? b1[co] : b2[co];
    }
}

// Y[j-j0][n][c'] = (xin @ B_j)[n][orig(c')], bf16, cols permuted.
__global__ __launch_bounds__(256) void xw_kernel(const unsigned short* __restrict__ xin,
                                                 const unsigned short* __restrict__ WTa,
                                                 unsigned short* __restrict__ Y,
                                                 int N, int j0, int j1) {
    __shared__ unsigned short Ws[128][136];
    const int t = threadIdx.x;
    const int w = t >> 6, l = t & 63;
    const int m_base = blockIdx.x * 128;
    const int colb = l & 15, quad = l >> 4;
    const f32x4 fz = {0.f, 0.f, 0.f, 0.f};

    int row0 = m_base + w * 32 + colb;
    int row1 = row0 + 16;
    const unsigned short* xr0 = xin + (size_t)(row0 < N ? row0 : N - 1) * H;
    const unsigned short* xr1 = xin + (size_t)(row1 < N ? row1 : N - 1) * H;

    for (int j = j0; j < j1; ++j) {
        __syncthreads();
#pragma unroll
        for (int p = 0; p < 8; ++p) {
            int c = p * 256 + t;
            int f = c >> 4, k8 = (c & 15) * 8;
            *(u16x8*)&Ws[f][k8] = *(const u16x8*)&WTa[((size_t)j * H + f) * H + k8];
        }
        __syncthreads();
        f32x4 acc[2][8];
#pragma unroll
        for (int mi = 0; mi < 2; ++mi)
#pragma unroll
            for (int n = 0; n < 8; ++n) acc[mi][n] = fz;
#pragma unroll
        for (int ks = 0; ks < 4; ++ks) {
            int kl = ks * 32 + quad * 8;
            bf16x8 a0 = *(const bf16x8*)&xr0[kl];
            bf16x8 a1 = *(const bf16x8*)&xr1[kl];
#pragma unroll
            for (int n = 0; n < 8; ++n) {
                bf16x8 b = *(const bf16x8*)&Ws[n * 16 + colb][kl];
                acc[0][n] = __builtin_amdgcn_mfma_f32_16x16x32_bf16(a0, b, acc[0][n], 0, 0, 0);
                acc[1][n] = __builtin_amdgcn_mfma_f32_16x16x32_bf16(a1, b, acc[1][n], 0, 0, 0);
            }
        }
        unsigned short* Yj = Y + (size_t)(j - j0) * N * H;
#pragma unroll
        for (int mi = 0; mi < 2; ++mi) {
#pragma unroll
            for (int i = 0; i < 4; ++i) {
                int row = m_base + w * 32 + mi * 16 + quad * 4 + i;
                if (row < N) {
                    u16x8 o;
#pragma unroll
                    for (int n = 0; n < 8; ++n) o[n] = f2bf(acc[mi][n][i]);
                    *(u16x8*)&Yj[(size_t)row * H + colb * 8] = o;  // col' = colb*8 + n
                }
            }
        }
    }
}

// one 16-lane group per dst; packed edges (src | r<<20), dst-contiguous.
__global__ __launch_bounds__(256) void gather_kernel(const unsigned short* __restrict__ Y,
                                                     const float* __restrict__ inv,
                                                     const int* __restrict__ rowptr,
                                                     const int* __restrict__ packed,
                                                     const float* __restrict__ biasP,
                                                     float* __restrict__ accf,
                                                     float* __restrict__ outf,
                                                     unsigned short* __restrict__ outb,
                                                     int N, int relu, int j0, int j1, int final_pass) {
    const int t = threadIdx.x;
    const int l = t & 63;
    int d = blockIdx.x * 16 + (t >> 4);
    if (d >= N) return;
    const int fl = l & 15;
    const int kc = fl * 8;
    const int gbase = l & 48;
    int rp = 0;
    if (fl < 2) rp = rowptr[d + fl];
    float ivl = 0.f;
    if (fl < 8) ivl = inv[(size_t)d * RREL + fl];
    int beg = __shfl(rp, gbase);
    int end = __shfl(rp, gbase + 1);
    const int jr = (j1 < RREL) ? j1 : RREL;
    float tot[8] = {};
    for (int i = beg; i < end; i += 16) {
        int pk = (i + fl < end) ? packed[i + fl] : 0;
        int m = end - i;
        if (m > 16) m = 16;
        int e = 0;
        for (; e + 1 < m; e += 2) {
            int v0 = __shfl(pk, gbase + e);
            int v1 = __shfl(pk, gbase + e + 1);
            int s0 = v0 & 0xFFFFF, r0 = v0 >> 20;
            int s1 = v1 & 0xFFFFF, r1 = v1 >> 20;
            if (r0 >= j0 && r0 < jr) {
                float iv = __shfl(ivl, gbase + r0);
                u16x8 v = *(const u16x8*)&Y[((size_t)(r0 - j0) * N + s0) * H + kc];
#pragma unroll
                for (int j = 0; j < 8; ++j) tot[j] += iv * bf2f((unsigned short)v[j]);
            }
            if (r1 >= j0 && r1 < jr) {
                float iv = __shfl(ivl, gbase + r1);
                u16x8 v = *(const u16x8*)&Y[((size_t)(r1 - j0) * N + s1) * H + kc];
#pragma unroll
                for (int j = 0; j < 8; ++j) tot[j] += iv * bf2f((unsigned short)v[j]);
            }
        }
        if (e < m) {
            int v0 = __shfl(pk, gbase + e);
            int s0 = v0 & 0xFFFFF, r0 = v0 >> 20;
            if (r0 >= j0 && r0 < jr) {
                float iv = __shfl(ivl, gbase + r0);
                u16x8 v = *(const u16x8*)&Y[((size_t)(r0 - j0) * N + s0) * H + kc];
#pragma unroll
                for (int j = 0; j < 8; ++j) tot[j] += iv * bf2f((unsigned short)v[j]);
            }
        }
    }
    if (j1 == NJ) {
        u16x8 vr = *(const u16x8*)&Y[((size_t)(RREL - j0) * N + d) * H + kc];
#pragma unroll
        for (int j = 0; j < 8; ++j) tot[j] += bf2f((unsigned short)vr[j]);
    }
    if (j0 > 0) {
        f32x4 p0 = *(const f32x4*)&accf[(size_t)d * H + kc];
        f32x4 p1 = *(const f32x4*)&accf[(size_t)d * H + kc + 4];
#pragma unroll
        for (int j = 0; j < 4; ++j) { tot[j] += p0[j]; tot[4 + j] += p1[j]; }
    }
    if (final_pass) {
        f32x4 b0 = *(const f32x4*)&biasP[kc];
        f32x4 b1 = *(const f32x4*)&biasP[kc + 4];
#pragma unroll
        for (int j = 0; j < 4; ++j) { tot[j] += b0[j]; tot[4 + j] += b1[j]; }
        if (relu) {
#pragma unroll
            for (int j = 0; j < 8; ++j) tot[j] = fmaxf(tot[j], 0.f);
        }
        if (outf) {
#pragma unroll
            for (int j = 0; j < 8; ++j) outf[(size_t)d * H + j * 16 + fl] = tot[j];
        } else {
            u16x8 o;
#pragma unroll
            for (int j = 0; j < 8; ++j) o[j] = f2bf(tot[j]);
            *(u16x8*)&outb[(size_t)d * H + kc] = o;
        }
    } else {
        f32x4 o0, o1;
#pragma unroll
        for (int j = 0; j < 4; ++j) { o0[j] = tot[j]; o1[j] = tot[4 + j]; }
        *(f32x4*)&accf[(size_t)d * H + kc] = o0;
        *(f32x4*)&accf[(size_t)d * H + kc + 4] = o1;
    }
}

extern "C" void kernel_launch(void* const* d_in, const int* in_sizes, int n_in,
                              void* d_out, int out_size, void* d_ws, size_t ws_size,
                              hipStream_t stream) {
    const int* edge_index = (const int*)d_in[0];
    const int* edge_type  = (const int*)d_in[1];
    const float* node_emb = (const float*)d_in[2];
    const float* W1    = (const float*)d_in[3];
    const float* root1 = (const float*)d_in[4];
    const float* b1    = (const float*)d_in[5];
    const float* W2    = (const float*)d_in[6];
    const float* root2 = (const float*)d_in[7];
    const float* b2    = (const float*)d_in[8];
    float* out = (float*)d_out;

    const int E = in_sizes[1];
    const int N = in_sizes[2] / H;

    char* base = (char*)d_ws;
    size_t off = 0;
    auto take = [&](size_t bytes) { size_t o = off; off = (off + bytes + 63) & ~(size_t)63; return o; };
    int*   cnt_pad = (int*)  (base + take((size_t)N * RREL * CPAD * 4));  // count, then cursor
    int*   rploc   = (int*)  (base + take((size_t)N * 4));
    int*   bsum    = (int*)  (base + take(256 * 4));
    int*   boff    = (int*)  (base + take(256 * 4));
    int*   rowptr  = (int*)  (base + take(((size_t)N + 1) * 4));
    int*   rowptr2 = (int*)  (base + take((size_t)N * RREL * 4));
    float* inv     = (float*)(base + take((size_t)N * RREL * 4));
    int*   packed  = (int*)  (base + take((size_t)E * 4));
    unsigned short* WTa1 = (unsigned short*)(base + take((size_t)NJ * H * H * 2));
    unsigned short* WTa2 = (unsigned short*)(base + take((size_t)NJ * H * H * 2));
    float* biasP   = (float*)(base + take(2 * H * 4));
    unsigned short* xb  = (unsigned short*)(base + take((size_t)N * H * 2));
    unsigned short* hb  = (unsigned short*)(base + take((size_t)N * H * 2));

    // Y: full 9-slab if it fits, else fp32 accumulator + relation chunks
    size_t fixed_off = off;
    unsigned short* Y;
    float* accf = nullptr;
    int rc;
    size_t availA = (ws_size > fixed_off) ? ws_size - fixed_off : 0;
    if (availA >= (size_t)NJ * N * H * 2) {
        Y = (unsigned short*)(base + fixed_off);
        rc = NJ;
    } else {
        accf = (float*)(base + fixed_off);
        size_t off2 = fixed_off + (((size_t)N * H * 4 + 63) & ~(size_t)63);
        Y = (unsigned short*)(base + off2);
        size_t availB = (ws_size > off2) ? ws_size - off2 : 0;
        rc = (int)(availB / ((size_t)N * H * 2));
        if (rc > RREL) rc = RREL;
        if (rc < 1) rc = 1;
    }

    const int nbScan = (N + 255) / 256;

    zero_kernel<<<2048, 256, 0, stream>>>(cnt_pad, (long)N * RREL * CPAD);
    count_kernel<<<(E + 255) / 256, 256, 0, stream>>>(edge_index, edge_type, cnt_pad, E);
    scan_block_kernel<<<nbScan, 256, 0, stream>>>(cnt_pad, rploc, bsum, N);
    scan_top_kernel<<<1, 256, 0, stream>>>(bsum, boff, nbScan);
    finalize_kernel<<<nbScan, 256, 0, stream>>>(cnt_pad, rploc, boff, rowptr, rowptr2, inv, N);
    fill_kernel<<<(E + 255) / 256, 256, 0, stream>>>(edge_index, edge_type, cnt_pad, rowptr2, packed, E);
    wcat_kernel<<<(NJ * H * H + 2 * H + 255) / 256, 256, 0, stream>>>(W1, root1, W2, root2, b1, b2,
                                                                      WTa1, WTa2, biasP);
    tobf_kernel<<<1024, 256, 0, stream>>>(node_emb, xb, (long)N * H);

    const int gx = (N + 127) / 128;
    const int gg = (N + 15) / 16;

    auto run_layer = [&](const unsigned short* xin, const unsigned short* WTa, const float* bp,
                         float* of, unsigned short* ob, int relu) {
        for (int j0 = 0; j0 < NJ; j0 += rc) {
            int j1 = (j0 + rc < NJ) ? j0 + rc : NJ;
            int fin = (j1 == NJ);
            xw_kernel<<<gx, 256, 0, stream>>>(xin, WTa, Y, N, j0, j1);
            gather_kernel<<<gg, 256, 0, stream>>>(Y, inv, rowptr, packed, bp, accf,
                                                  fin ? of : nullptr, fin ? ob : nullptr,
                                                  N, relu, j0, j1, fin);
        }
    };

    run_layer(xb, WTa1, biasP, nullptr, hb, 1);
    run_layer(hb, WTa2, biasP + H, out, nullptr, 0);
}

// Round 9
// 300.460 us; speedup vs baseline: 1.0209x; 1.0209x over previous
//
#include <hip/hip_runtime.h>

#define H 128
#define RREL 8
#define NJ 9        // 8 relations + root
#define CURPAD 16   // ints per padded fill-cursor slot (64 B stride)

typedef short bf16x8 __attribute__((ext_vector_type(8)));
typedef float f32x4 __attribute__((ext_vector_type(4)));
typedef unsigned short u16x8 __attribute__((ext_vector_type(8)));

static __device__ __forceinline__ unsigned short f2bf(float f) {
    unsigned int u = __float_as_uint(f);
    unsigned int r = (u + 0x7fffu + ((u >> 16) & 1u)) >> 16;
    return (unsigned short)r;
}
static __device__ __forceinline__ float bf2f(unsigned short u) {
    return __uint_as_float(((unsigned int)u) << 16);
}

__global__ void zero_kernel(int* p, long n) {
    long i = (long)blockIdx.x * blockDim.x + threadIdx.x;
    long stride = (long)gridDim.x * blockDim.x;
    for (; i < n; i += stride) p[i] = 0;
}

__global__ void count_kernel(const int* __restrict__ ei, const int* __restrict__ et,
                             int* __restrict__ cnt, int E) {
    int e = blockIdx.x * 256 + threadIdx.x;
    if (e >= E) return;
    int d = ei[E + e];
    int r = et[e];
    atomicAdd(&cnt[(size_t)d * RREL + r], 1);
}

__global__ void scan_block_kernel(const int* __restrict__ cnt, int* __restrict__ rploc,
                                  int* __restrict__ bsum, int N) {
    __shared__ int s[256];
    int t = threadIdx.x;
    int d = blockIdx.x * 256 + t;
    int v = 0;
    if (d < N) {
#pragma unroll
        for (int r = 0; r < RREL; ++r) v += cnt[(size_t)d * RREL + r];
    }
    s[t] = v;
    __syncthreads();
#pragma unroll
    for (int off = 1; off < 256; off <<= 1) {
        int u = 0;
        if (t >= off) u = s[t - off];
        __syncthreads();
        s[t] += u;
        __syncthreads();
    }
    if (d < N) rploc[d] = s[t] - v;
    if (t == 255) bsum[blockIdx.x] = s[255];
}

__global__ void scan_top_kernel(const int* __restrict__ bsum, int* __restrict__ boff, int nb) {
    __shared__ int s[256];
    int t = threadIdx.x;
    int v = (t < nb) ? bsum[t] : 0;
    s[t] = v;
    __syncthreads();
#pragma unroll
    for (int off = 1; off < 256; off <<= 1) {
        int u = 0;
        if (t >= off) u = s[t - off];
        __syncthreads();
        s[t] += u;
        __syncthreads();
    }
    boff[t] = s[t] - v;
}

// rowptr[d] = global dst-segment start; inv[d*8+r] = 1/max(cnt,1); rowptr[N] = E
__global__ void finalize_kernel(const int* __restrict__ cnt, const int* __restrict__ rploc,
                                const int* __restrict__ boff, int* __restrict__ rowptr,
                                float* __restrict__ inv, int N) {
    int d = blockIdx.x * 256 + threadIdx.x;
    if (d >= N) return;
    int rp = rploc[d] + boff[d >> 8];
    rowptr[d] = rp;
    int deg = 0;
#pragma unroll
    for (int r = 0; r < RREL; ++r) {
        int c = cnt[(size_t)d * RREL + r];
        inv[(size_t)d * RREL + r] = 1.0f / (float)max(c, 1);
        deg += c;
    }
    if (d == N - 1) rowptr[N] = rp + deg;
}

// packed[pos] = src | (rel<<20), binned by dst; cursor padded to 64 B per dst
__global__ void fill_kernel(const int* __restrict__ ei, const int* __restrict__ et,
                            int* __restrict__ cursor_pad, const int* __restrict__ rowptr,
                            int* __restrict__ packed, int E) {
    int e = blockIdx.x * 256 + threadIdx.x;
    if (e >= E) return;
    int d = ei[E + e];
    int pos = rowptr[d] + atomicAdd(&cursor_pad[(size_t)d << 4], 1);
    packed[pos] = ei[e] | (et[e] << 20);
}

__global__ void tobf_kernel(const float* __restrict__ x, unsigned short* __restrict__ xb, long n) {
    long i = (long)blockIdx.x * blockDim.x + threadIdx.x;
    long stride = (long)gridDim.x * blockDim.x;
    for (; i < n; i += stride) xb[i] = f2bf(x[i]);
}

// WTa1[j][f][k] = W1[j][k][f] / root1[k][f]   (normal K)
// WTa2[j][f][k'] = W2[j][orig(k')][f] / root2[orig(k')][f]   (orig(k')=(k'&7)*16+(k'>>3))
// biasP[0][c'] = b1[orig(c')], biasP[1][c'] = b2[orig(c')]
__global__ void wcat_kernel(const float* __restrict__ W1, const float* __restrict__ r1,
                            const float* __restrict__ W2, const float* __restrict__ r2,
                            const float* __restrict__ b1, const float* __restrict__ b2,
                            unsigned short* __restrict__ WTa1, unsigned short* __restrict__ WTa2,
                            float* __restrict__ biasP) {
    int id = blockIdx.x * 256 + threadIdx.x;
    const int per = NJ * H * H;
    if (id < per) {
        int j = id / (H * H);
        int fk = id - j * (H * H);
        int f = fk >> 7, k = fk & 127;
        float v = (j < RREL) ? W1[((size_t)j * H + k) * H + f] : r1[(size_t)k * H + f];
        WTa1[id] = f2bf(v);
        int ko = (k & 7) * 16 + (k >> 3);
        float v2 = (j < RREL) ? W2[((size_t)j * H + ko) * H + f] : r2[(size_t)ko * H + f];
        WTa2[id] = f2bf(v2);
    } else if (id < per + 2 * H) {
        int c = id - per;
        int cp = c & 127;
        int co = (cp & 7) * 16 + (cp >> 3);
        biasP[c] = (c < H) ? b1[co] : b2[co];
    }
}

// Y[j-j0][n][c'] = (xin @ B_j)[n][orig(c')], bf16, cols permuted.
__global__ __launch_bounds__(256) void xw_kernel(const unsigned short* __restrict__ xin,
                                                 const unsigned short* __restrict__ WTa,
                                                 unsigned short* __restrict__ Y,
                                                 int N, int j0, int j1) {
    __shared__ unsigned short Ws[128][136];
    const int t = threadIdx.x;
    const int w = t >> 6, l = t & 63;
    const int m_base = blockIdx.x * 128;
    const int colb = l & 15, quad = l >> 4;
    const f32x4 fz = {0.f, 0.f, 0.f, 0.f};

    int row0 = m_base + w * 32 + colb;
    int row1 = row0 + 16;
    const unsigned short* xr0 = xin + (size_t)(row0 < N ? row0 : N - 1) * H;
    const unsigned short* xr1 = xin + (size_t)(row1 < N ? row1 : N - 1) * H;

    for (int j = j0; j < j1; ++j) {
        __syncthreads();
#pragma unroll
        for (int p = 0; p < 8; ++p) {
            int c = p * 256 + t;
            int f = c >> 4, k8 = (c & 15) * 8;
            *(u16x8*)&Ws[f][k8] = *(const u16x8*)&WTa[((size_t)j * H + f) * H + k8];
        }
        __syncthreads();
        f32x4 acc[2][8];
#pragma unroll
        for (int mi = 0; mi < 2; ++mi)
#pragma unroll
            for (int n = 0; n < 8; ++n) acc[mi][n] = fz;
#pragma unroll
        for (int ks = 0; ks < 4; ++ks) {
            int kl = ks * 32 + quad * 8;
            bf16x8 a0 = *(const bf16x8*)&xr0[kl];
            bf16x8 a1 = *(const bf16x8*)&xr1[kl];
#pragma unroll
            for (int n = 0; n < 8; ++n) {
                bf16x8 b = *(const bf16x8*)&Ws[n * 16 + colb][kl];
                acc[0][n] = __builtin_amdgcn_mfma_f32_16x16x32_bf16(a0, b, acc[0][n], 0, 0, 0);
                acc[1][n] = __builtin_amdgcn_mfma_f32_16x16x32_bf16(a1, b, acc[1][n], 0, 0, 0);
            }
        }
        unsigned short* Yj = Y + (size_t)(j - j0) * N * H;
#pragma unroll
        for (int mi = 0; mi < 2; ++mi) {
#pragma unroll
            for (int i = 0; i < 4; ++i) {
                int row = m_base + w * 32 + mi * 16 + quad * 4 + i;
                if (row < N) {
                    u16x8 o;
#pragma unroll
                    for (int n = 0; n < 8; ++n) o[n] = f2bf(acc[mi][n][i]);
                    *(u16x8*)&Yj[(size_t)row * H + colb * 8] = o;  // col' = colb*8 + n
                }
            }
        }
    }
}

// one 16-lane group per dst; packed edges (src | r<<20), dst-contiguous.
// sentinel pk=-1 -> r=-1 fails range check; flat 16-slot x unroll-4 inner loop.
__global__ __launch_bounds__(256) void gather_kernel(const unsigned short* __restrict__ Y,
                                                     const float* __restrict__ inv,
                                                     const int* __restrict__ rowptr,
                                                     const int* __restrict__ packed,
                                                     const float* __restrict__ biasP,
                                                     float* __restrict__ accf,
                                                     float* __restrict__ outf,
                                                     unsigned short* __restrict__ outb,
                                                     int N, int relu, int j0, int j1, int final_pass) {
    const int t = threadIdx.x;
    const int l = t & 63;
    int d = blockIdx.x * 16 + (t >> 4);
    if (d >= N) return;
    const int fl = l & 15;
    const int kc = fl * 8;
    const int gbase = l & 48;
    int rp = 0;
    if (fl < 2) rp = rowptr[d + fl];
    float ivl = 0.f;
    if (fl < 8) ivl = inv[(size_t)d * RREL + fl];
    int beg = __shfl(rp, gbase);
    int end = __shfl(rp, gbase + 1);
    const int jr = (j1 < RREL) ? j1 : RREL;
    float tot[8] = {};
    for (int i = beg; i < end; i += 16) {
        int pk = (i + fl < end) ? packed[i + fl] : -1;
#pragma unroll
        for (int e = 0; e < 16; e += 4) {
            int v0 = __shfl(pk, gbase + e);
            int v1 = __shfl(pk, gbase + e + 1);
            int v2 = __shfl(pk, gbase + e + 2);
            int v3 = __shfl(pk, gbase + e + 3);
            int s0 = v0 & 0xFFFFF, r0 = v0 >> 20;
            int s1 = v1 & 0xFFFFF, r1 = v1 >> 20;
            int s2 = v2 & 0xFFFFF, r2 = v2 >> 20;
            int s3 = v3 & 0xFFFFF, r3 = v3 >> 20;
            if (r0 >= j0 && r0 < jr) {
                float iv = __shfl(ivl, gbase + r0);
                u16x8 v = *(const u16x8*)&Y[((size_t)(r0 - j0) * N + s0) * H + kc];
#pragma unroll
                for (int j = 0; j < 8; ++j) tot[j] += iv * bf2f((unsigned short)v[j]);
            }
            if (r1 >= j0 && r1 < jr) {
                float iv = __shfl(ivl, gbase + r1);
                u16x8 v = *(const u16x8*)&Y[((size_t)(r1 - j0) * N + s1) * H + kc];
#pragma unroll
                for (int j = 0; j < 8; ++j) tot[j] += iv * bf2f((unsigned short)v[j]);
            }
            if (r2 >= j0 && r2 < jr) {
                float iv = __shfl(ivl, gbase + r2);
                u16x8 v = *(const u16x8*)&Y[((size_t)(r2 - j0) * N + s2) * H + kc];
#pragma unroll
                for (int j = 0; j < 8; ++j) tot[j] += iv * bf2f((unsigned short)v[j]);
            }
            if (r3 >= j0 && r3 < jr) {
                float iv = __shfl(ivl, gbase + r3);
                u16x8 v = *(const u16x8*)&Y[((size_t)(r3 - j0) * N + s3) * H + kc];
#pragma unroll
                for (int j = 0; j < 8; ++j) tot[j] += iv * bf2f((unsigned short)v[j]);
            }
        }
    }
    if (j1 == NJ) {
        u16x8 vr = *(const u16x8*)&Y[((size_t)(RREL - j0) * N + d) * H + kc];
#pragma unroll
        for (int j = 0; j < 8; ++j) tot[j] += bf2f((unsigned short)vr[j]);
    }
    if (j0 > 0) {
        f32x4 p0 = *(const f32x4*)&accf[(size_t)d * H + kc];
        f32x4 p1 = *(const f32x4*)&accf[(size_t)d * H + kc + 4];
#pragma unroll
        for (int j = 0; j < 4; ++j) { tot[j] += p0[j]; tot[4 + j] += p1[j]; }
    }
    if (final_pass) {
        f32x4 b0 = *(const f32x4*)&biasP[kc];
        f32x4 b1 = *(const f32x4*)&biasP[kc + 4];
#pragma unroll
        for (int j = 0; j < 4; ++j) { tot[j] += b0[j]; tot[4 + j] += b1[j]; }
        if (relu) {
#pragma unroll
            for (int j = 0; j < 8; ++j) tot[j] = fmaxf(tot[j], 0.f);
        }
        if (outf) {
            // unscramble: stored index kc+j holds orig col j*16+fl
#pragma unroll
            for (int j = 0; j < 8; ++j) outf[(size_t)d * H + j * 16 + fl] = tot[j];
        } else {
            u16x8 o;
#pragma unroll
            for (int j = 0; j < 8; ++j) o[j] = f2bf(tot[j]);
            *(u16x8*)&outb[(size_t)d * H + kc] = o;
        }
    } else {
        f32x4 o0, o1;
#pragma unroll
        for (int j = 0; j < 4; ++j) { o0[j] = tot[j]; o1[j] = tot[4 + j]; }
        *(f32x4*)&accf[(size_t)d * H + kc] = o0;
        *(f32x4*)&accf[(size_t)d * H + kc + 4] = o1;
    }
}

extern "C" void kernel_launch(void* const* d_in, const int* in_sizes, int n_in,
                              void* d_out, int out_size, void* d_ws, size_t ws_size,
                              hipStream_t stream) {
    const int* edge_index = (const int*)d_in[0];
    const int* edge_type  = (const int*)d_in[1];
    const float* node_emb = (const float*)d_in[2];
    const float* W1    = (const float*)d_in[3];
    const float* root1 = (const float*)d_in[4];
    const float* b1    = (const float*)d_in[5];
    const float* W2    = (const float*)d_in[6];
    const float* root2 = (const float*)d_in[7];
    const float* b2    = (const float*)d_in[8];
    float* out = (float*)d_out;

    const int E = in_sizes[1];
    const int N = in_sizes[2] / H;

    char* base = (char*)d_ws;
    size_t off = 0;
    auto take = [&](size_t bytes) { size_t o = off; off = (off + bytes + 63) & ~(size_t)63; return o; };
    int*   cnt        = (int*)  (base + take((size_t)N * RREL * 4));          // compact counts
    int*   cursor_pad = (int*)  (base + take((size_t)N * CURPAD * 4));        // adjacent: one zero pass
    int*   rploc      = (int*)  (base + take((size_t)N * 4));
    int*   bsum       = (int*)  (base + take(256 * 4));
    int*   boff       = (int*)  (base + take(256 * 4));
    int*   rowptr     = (int*)  (base + take(((size_t)N + 1) * 4));
    float* inv        = (float*)(base + take((size_t)N * RREL * 4));
    int*   packed     = (int*)  (base + take((size_t)E * 4));
    unsigned short* WTa1 = (unsigned short*)(base + take((size_t)NJ * H * H * 2));
    unsigned short* WTa2 = (unsigned short*)(base + take((size_t)NJ * H * H * 2));
    float* biasP      = (float*)(base + take(2 * H * 4));
    unsigned short* xb = (unsigned short*)(base + take((size_t)N * H * 2));
    unsigned short* hb = (unsigned short*)(base + take((size_t)N * H * 2));

    // Y: full 9-slab if it fits, else fp32 accumulator + relation chunks
    size_t fixed_off = off;
    unsigned short* Y;
    float* accf = nullptr;
    int rc;
    size_t availA = (ws_size > fixed_off) ? ws_size - fixed_off : 0;
    if (availA >= (size_t)NJ * N * H * 2) {
        Y = (unsigned short*)(base + fixed_off);
        rc = NJ;
    } else {
        accf = (float*)(base + fixed_off);
        size_t off2 = fixed_off + (((size_t)N * H * 4 + 63) & ~(size_t)63);
        Y = (unsigned short*)(base + off2);
        size_t availB = (ws_size > off2) ? ws_size - off2 : 0;
        rc = (int)(availB / ((size_t)N * H * 2));
        if (rc > RREL) rc = RREL;
        if (rc < 1) rc = 1;
    }

    const int nbScan = (N + 255) / 256;

    zero_kernel<<<1024, 256, 0, stream>>>(cnt, (long)N * (RREL + CURPAD));  // cnt + cursor_pad
    count_kernel<<<(E + 255) / 256, 256, 0, stream>>>(edge_index, edge_type, cnt, E);
    scan_block_kernel<<<nbScan, 256, 0, stream>>>(cnt, rploc, bsum, N);
    scan_top_kernel<<<1, 256, 0, stream>>>(bsum, boff, nbScan);
    finalize_kernel<<<nbScan, 256, 0, stream>>>(cnt, rploc, boff, rowptr, inv, N);
    fill_kernel<<<(E + 255) / 256, 256, 0, stream>>>(edge_index, edge_type, cursor_pad, rowptr, packed, E);
    wcat_kernel<<<(NJ * H * H + 2 * H + 255) / 256, 256, 0, stream>>>(W1, root1, W2, root2, b1, b2,
                                                                      WTa1, WTa2, biasP);
    tobf_kernel<<<1024, 256, 0, stream>>>(node_emb, xb, (long)N * H);

    const int gx = (N + 127) / 128;
    const int gg = (N + 15) / 16;

    auto run_layer = [&](const unsigned short* xin, const unsigned short* WTa, const float* bp,
                         float* of, unsigned short* ob, int relu) {
        for (int j0 = 0; j0 < NJ; j0 += rc) {
            int j1 = (j0 + rc < NJ) ? j0 + rc : NJ;
            int fin = (j1 == NJ);
            xw_kernel<<<gx, 256, 0, stream>>>(xin, WTa, Y, N, j0, j1);
            gather_kernel<<<gg, 256, 0, stream>>>(Y, inv, rowptr, packed, bp, accf,
                                                  fin ? of : nullptr, fin ? ob : nullptr,
                                                  N, relu, j0, j1, fin);
        }
    };

    run_layer(xb, WTa1, biasP, nullptr, hb, 1);
    run_layer(hb, WTa2, biasP + H, out, nullptr, 0);
}

// Round 12
// 297.883 us; speedup vs baseline: 1.0297x; 1.0087x over previous
//
#include <hip/hip_runtime.h>

#define H 128
#define RREL 8
#define NJ 9        // 8 relations + root
#define CURPAD 16   // ints per padded fill-cursor slot (64 B stride)

typedef short bf16x8 __attribute__((ext_vector_type(8)));
typedef float f32x4 __attribute__((ext_vector_type(4)));
typedef unsigned short u16x8 __attribute__((ext_vector_type(8)));

static __device__ __forceinline__ unsigned short f2bf(float f) {
    unsigned int u = __float_as_uint(f);
    unsigned int r = (u + 0x7fffu + ((u >> 16) & 1u)) >> 16;
    return (unsigned short)r;
}
static __device__ __forceinline__ float bf2f(unsigned short u) {
    return __uint_as_float(((unsigned int)u) << 16);
}

__global__ void zero_kernel(int* p, long n) {
    long i = (long)blockIdx.x * blockDim.x + threadIdx.x;
    long stride = (long)gridDim.x * blockDim.x;
    for (; i < n; i += stride) p[i] = 0;
}

__global__ void count_kernel(const int* __restrict__ ei, const int* __restrict__ et,
                             int* __restrict__ cnt, int E) {
    int e = blockIdx.x * 256 + threadIdx.x;
    if (e >= E) return;
    int d = ei[E + e];
    int r = et[e];
    atomicAdd(&cnt[(size_t)d * RREL + r], 1);
}

__global__ void scan_block_kernel(const int* __restrict__ cnt, int* __restrict__ rploc,
                                  int* __restrict__ bsum, int N) {
    __shared__ int s[256];
    int t = threadIdx.x;
    int d = blockIdx.x * 256 + t;
    int v = 0;
    if (d < N) {
#pragma unroll
        for (int r = 0; r < RREL; ++r) v += cnt[(size_t)d * RREL + r];
    }
    s[t] = v;
    __syncthreads();
#pragma unroll
    for (int off = 1; off < 256; off <<= 1) {
        int u = 0;
        if (t >= off) u = s[t - off];
        __syncthreads();
        s[t] += u;
        __syncthreads();
    }
    if (d < N) rploc[d] = s[t] - v;
    if (t == 255) bsum[blockIdx.x] = s[255];
}

__global__ void scan_top_kernel(const int* __restrict__ bsum, int* __restrict__ boff, int nb) {
    __shared__ int s[256];
    int t = threadIdx.x;
    int v = (t < nb) ? bsum[t] : 0;
    s[t] = v;
    __syncthreads();
#pragma unroll
    for (int off = 1; off < 256; off <<= 1) {
        int u = 0;
        if (t >= off) u = s[t - off];
        __syncthreads();
        s[t] += u;
        __syncthreads();
    }
    boff[t] = s[t] - v;
}

// rowptr[d] = global dst-segment start; inv[d*8+r] = 1/max(cnt,1); rowptr[N] = E
__global__ void finalize_kernel(const int* __restrict__ cnt, const int* __restrict__ rploc,
                                const int* __restrict__ boff, int* __restrict__ rowptr,
                                float* __restrict__ inv, int N) {
    int d = blockIdx.x * 256 + threadIdx.x;
    if (d >= N) return;
    int rp = rploc[d] + boff[d >> 8];
    rowptr[d] = rp;
    int deg = 0;
#pragma unroll
    for (int r = 0; r < RREL; ++r) {
        int c = cnt[(size_t)d * RREL + r];
        inv[(size_t)d * RREL + r] = 1.0f / (float)max(c, 1);
        deg += c;
    }
    if (d == N - 1) rowptr[N] = rp + deg;
}

// packed[pos] = src | (rel<<20), binned by dst; cursor padded to 64 B per dst
__global__ void fill_kernel(const int* __restrict__ ei, const int* __restrict__ et,
                            int* __restrict__ cursor_pad, const int* __restrict__ rowptr,
                            int* __restrict__ packed, int E) {
    int e = blockIdx.x * 256 + threadIdx.x;
    if (e >= E) return;
    int d = ei[E + e];
    int pos = rowptr[d] + atomicAdd(&cursor_pad[(size_t)d << 4], 1);
    packed[pos] = ei[e] | (et[e] << 20);
}

__global__ void tobf_kernel(const float* __restrict__ x, unsigned short* __restrict__ xb, long n) {
    long i = (long)blockIdx.x * blockDim.x + threadIdx.x;
    long stride = (long)gridDim.x * blockDim.x;
    for (; i < n; i += stride) xb[i] = f2bf(x[i]);
}

// WTa1[j][f][k] = W1[j][k][f] / root1[k][f]   (normal K)
// WTa2[j][f][k'] = W2[j][orig(k')][f] / root2[orig(k')][f]   (orig(k')=(k'&7)*16+(k'>>3))
// biasP[0][c'] = b1[orig(c')], biasP[1][c'] = b2[orig(c')]
__global__ void wcat_kernel(const float* __restrict__ W1, const float* __restrict__ r1,
                            const float* __restrict__ W2, const float* __restrict__ r2,
                            const float* __restrict__ b1, const float* __restrict__ b2,
                            unsigned short* __restrict__ WTa1, unsigned short* __restrict__ WTa2,
                            float* __restrict__ biasP) {
    int id = blockIdx.x * 256 + threadIdx.x;
    const int per = NJ * H * H;
    if (id < per) {
        int j = id / (H * H);
        int fk = id - j * (H * H);
        int f = fk >> 7, k = fk & 127;
        float v = (j < RREL) ? W1[((size_t)j * H + k) * H + f] : r1[(size_t)k * H + f];
        WTa1[id] = f2bf(v);
        int ko = (k & 7) * 16 + (k >> 3);
        float v2 = (j < RREL) ? W2[((size_t)j * H + ko) * H + f] : r2[(size_t)ko * H + f];
        WTa2[id] = f2bf(v2);
    } else if (id < per + 2 * H) {
        int c = id - per;
        int cp = c & 127;
        int co = (cp & 7) * 16 + (cp >> 3);
        biasP[c] = (c < H) ? b1[co] : b2[co];
    }
}

// Y[j-j0][n][c'] = (xin @ B_j)[n][orig(c')], bf16, cols permuted.
__global__ __launch_bounds__(256) void xw_kernel(const unsigned short* __restrict__ xin,
                                                 const unsigned short* __restrict__ WTa,
                                                 unsigned short* __restrict__ Y,
                                                 int N, int j0, int j1) {
    __shared__ unsigned short Ws[128][136];
    const int t = threadIdx.x;
    const int w = t >> 6, l = t & 63;
    const int m_base = blockIdx.x * 128;
    const int colb = l & 15, quad = l >> 4;
    const f32x4 fz = {0.f, 0.f, 0.f, 0.f};

    int row0 = m_base + w * 32 + colb;
    int row1 = row0 + 16;
    const unsigned short* xr0 = xin + (size_t)(row0 < N ? row0 : N - 1) * H;
    const unsigned short* xr1 = xin + (size_t)(row1 < N ? row1 : N - 1) * H;

    for (int j = j0; j < j1; ++j) {
        __syncthreads();
#pragma unroll
        for (int p = 0; p < 8; ++p) {
            int c = p * 256 + t;
            int f = c >> 4, k8 = (c & 15) * 8;
            *(u16x8*)&Ws[f][k8] = *(const u16x8*)&WTa[((size_t)j * H + f) * H + k8];
        }
        __syncthreads();
        f32x4 acc[2][8];
#pragma unroll
        for (int mi = 0; mi < 2; ++mi)
#pragma unroll
            for (int n = 0; n < 8; ++n) acc[mi][n] = fz;
#pragma unroll
        for (int ks = 0; ks < 4; ++ks) {
            int kl = ks * 32 + quad * 8;
            bf16x8 a0 = *(const bf16x8*)&xr0[kl];
            bf16x8 a1 = *(const bf16x8*)&xr1[kl];
#pragma unroll
            for (int n = 0; n < 8; ++n) {
                bf16x8 b = *(const bf16x8*)&Ws[n * 16 + colb][kl];
                acc[0][n] = __builtin_amdgcn_mfma_f32_16x16x32_bf16(a0, b, acc[0][n], 0, 0, 0);
                acc[1][n] = __builtin_amdgcn_mfma_f32_16x16x32_bf16(a1, b, acc[1][n], 0, 0, 0);
            }
        }
        unsigned short* Yj = Y + (size_t)(j - j0) * N * H;
#pragma unroll
        for (int mi = 0; mi < 2; ++mi) {
#pragma unroll
            for (int i = 0; i < 4; ++i) {
                int row = m_base + w * 32 + mi * 16 + quad * 4 + i;
                if (row < N) {
                    u16x8 o;
#pragma unroll
                    for (int n = 0; n < 8; ++n) o[n] = f2bf(acc[mi][n][i]);
                    *(u16x8*)&Yj[(size_t)row * H + colb * 8] = o;  // col' = colb*8 + n
                }
            }
        }
    }
}

// ONE WAVE PER DST. 4 groups of 16 lanes take the dst's edges with stride 4.
// LOCKSTEP-SAFE: all loop bounds rounded up to multiples of 4 so the 4 groups
// have identical trip counts — every __shfl source lane is active (inactive-lane
// bpermute reads are undefined and caused R11's failure). Sentinel pk=-1 (r=-1)
// zeroes out-of-range slots. Cross-group reduce via shfl_xor; group 0 epilogue.
__global__ __launch_bounds__(256) void gather_kernel(const unsigned short* __restrict__ Y,
                                                     const float* __restrict__ inv,
                                                     const int* __restrict__ rowptr,
                                                     const int* __restrict__ packed,
                                                     const float* __restrict__ biasP,
                                                     float* __restrict__ accf,
                                                     float* __restrict__ outf,
                                                     unsigned short* __restrict__ outb,
                                                     int N, int relu, int j0, int j1, int final_pass) {
    const int t = threadIdx.x;
    const int w = t >> 6, l = t & 63;
    int d = blockIdx.x * 4 + w;
    if (d >= N) return;
    const int g = l >> 4, fl = l & 15;
    const int kc = fl * 8;
    const int gb = l & 48;
    int beg = rowptr[d], end = rowptr[d + 1];
    float ivl = (fl < 8) ? inv[(size_t)d * RREL + fl] : 0.f;
    int pkb = (beg + l < end) ? packed[beg + l] : -1;  // prefetch first 64 edges
    const int cnt = end - beg;
    const int jr = (j1 < RREL) ? j1 : RREL;
    const int span = jr - j0;
    float tot[8] = {};
    int lim = cnt < 64 ? cnt : 64;
    int lim4 = (lim + 3) & ~3;                         // uniform trips across groups
    for (int idx = g; idx < lim4; idx += 4) {
        int pk = __shfl(pkb, idx);                     // idx<64; sentinel -1 if idx>=cnt
        int s = pk & 0xFFFFF;
        int r = pk >> 20;
        int rr = r - j0;
        bool ok = (unsigned)rr < (unsigned)span;
        float iv = __shfl(ivl, gb + (r & 7));
        iv = ok ? iv : 0.f;
        int rowc = ok ? rr : 0;
        int sc = ok ? s : 0;
        u16x8 v = *(const u16x8*)&Y[((size_t)rowc * N + sc) * H + kc];
#pragma unroll
        for (int j = 0; j < 8; ++j) tot[j] += iv * bf2f((unsigned short)v[j]);
    }
    // rare tail: degree > 64 (uniform trips, per-lane predicated load)
    int tail_n = cnt - 64;
    if (tail_n > 0) {
        int tailN = (tail_n + 3) & ~3;
        for (int o = g; o < tailN; o += 4) {
            int pk = (o < tail_n) ? packed[beg + 64 + o] : -1;
            int s = pk & 0xFFFFF;
            int r = pk >> 20;
            int rr = r - j0;
            bool ok = (unsigned)rr < (unsigned)span;
            float iv = __shfl(ivl, gb + (r & 7));
            iv = ok ? iv : 0.f;
            int rowc = ok ? rr : 0;
            int sc = ok ? s : 0;
            u16x8 v = *(const u16x8*)&Y[((size_t)rowc * N + sc) * H + kc];
#pragma unroll
            for (int j = 0; j < 8; ++j) tot[j] += iv * bf2f((unsigned short)v[j]);
        }
    }
    // reduce across the 4 groups (lanes with equal fl hold the same features)
#pragma unroll
    for (int j = 0; j < 8; ++j) {
        tot[j] += __shfl_xor(tot[j], 16);
        tot[j] += __shfl_xor(tot[j], 32);
    }
    if (g != 0) return;
    if (j1 == NJ) {
        u16x8 vr = *(const u16x8*)&Y[((size_t)(RREL - j0) * N + d) * H + kc];
#pragma unroll
        for (int j = 0; j < 8; ++j) tot[j] += bf2f((unsigned short)vr[j]);
    }
    if (j0 > 0) {
        f32x4 p0 = *(const f32x4*)&accf[(size_t)d * H + kc];
        f32x4 p1 = *(const f32x4*)&accf[(size_t)d * H + kc + 4];
#pragma unroll
        for (int j = 0; j < 4; ++j) { tot[j] += p0[j]; tot[4 + j] += p1[j]; }
    }
    if (final_pass) {
        f32x4 b0 = *(const f32x4*)&biasP[kc];
        f32x4 b1 = *(const f32x4*)&biasP[kc + 4];
#pragma unroll
        for (int j = 0; j < 4; ++j) { tot[j] += b0[j]; tot[4 + j] += b1[j]; }
        if (relu) {
#pragma unroll
            for (int j = 0; j < 8; ++j) tot[j] = fmaxf(tot[j], 0.f);
        }
        if (outf) {
            // unscramble: stored index kc+j holds orig col j*16+fl
#pragma unroll
            for (int j = 0; j < 8; ++j) outf[(size_t)d * H + j * 16 + fl] = tot[j];
        } else {
            u16x8 o;
#pragma unroll
            for (int j = 0; j < 8; ++j) o[j] = f2bf(tot[j]);
            *(u16x8*)&outb[(size_t)d * H + kc] = o;
        }
    } else {
        f32x4 o0, o1;
#pragma unroll
        for (int j = 0; j < 4; ++j) { o0[j] = tot[j]; o1[j] = tot[4 + j]; }
        *(f32x4*)&accf[(size_t)d * H + kc] = o0;
        *(f32x4*)&accf[(size_t)d * H + kc + 4] = o1;
    }
}

extern "C" void kernel_launch(void* const* d_in, const int* in_sizes, int n_in,
                              void* d_out, int out_size, void* d_ws, size_t ws_size,
                              hipStream_t stream) {
    const int* edge_index = (const int*)d_in[0];
    const int* edge_type  = (const int*)d_in[1];
    const float* node_emb = (const float*)d_in[2];
    const float* W1    = (const float*)d_in[3];
    const float* root1 = (const float*)d_in[4];
    const float* b1    = (const float*)d_in[5];
    const float* W2    = (const float*)d_in[6];
    const float* root2 = (const float*)d_in[7];
    const float* b2    = (const float*)d_in[8];
    float* out = (float*)d_out;

    const int E = in_sizes[1];
    const int N = in_sizes[2] / H;

    char* base = (char*)d_ws;
    size_t off = 0;
    auto take = [&](size_t bytes) { size_t o = off; off = (off + bytes + 63) & ~(size_t)63; return o; };
    int*   cnt        = (int*)  (base + take((size_t)N * RREL * 4));
    int*   cursor_pad = (int*)  (base + take((size_t)N * CURPAD * 4));   // adjacent: one zero pass
    int*   rploc      = (int*)  (base + take((size_t)N * 4));
    int*   bsum       = (int*)  (base + take(256 * 4));
    int*   boff       = (int*)  (base + take(256 * 4));
    int*   rowptr     = (int*)  (base + take(((size_t)N + 1) * 4));
    float* inv        = (float*)(base + take((size_t)N * RREL * 4));
    int*   packed     = (int*)  (base + take((size_t)E * 4));
    unsigned short* WTa1 = (unsigned short*)(base + take((size_t)NJ * H * H * 2));
    unsigned short* WTa2 = (unsigned short*)(base + take((size_t)NJ * H * H * 2));
    float* biasP      = (float*)(base + take(2 * H * 4));
    unsigned short* xb = (unsigned short*)(base + take((size_t)N * H * 2));
    unsigned short* hb = (unsigned short*)(base + take((size_t)N * H * 2));

    // Y: full 9-slab if it fits, else fp32 accumulator + relation chunks
    size_t fixed_off = off;
    unsigned short* Y;
    float* accf = nullptr;
    int rc;
    size_t availA = (ws_size > fixed_off) ? ws_size - fixed_off : 0;
    if (availA >= (size_t)NJ * N * H * 2) {
        Y = (unsigned short*)(base + fixed_off);
        rc = NJ;
    } else {
        accf = (float*)(base + fixed_off);
        size_t off2 = fixed_off + (((size_t)N * H * 4 + 63) & ~(size_t)63);
        Y = (unsigned short*)(base + off2);
        size_t availB = (ws_size > off2) ? ws_size - off2 : 0;
        rc = (int)(availB / ((size_t)N * H * 2));
        if (rc > RREL) rc = RREL;
        if (rc < 1) rc = 1;
    }

    const int nbScan = (N + 255) / 256;

    zero_kernel<<<1024, 256, 0, stream>>>(cnt, (long)N * (RREL + CURPAD));  // cnt + cursor_pad
    count_kernel<<<(E + 255) / 256, 256, 0, stream>>>(edge_index, edge_type, cnt, E);
    scan_block_kernel<<<nbScan, 256, 0, stream>>>(cnt, rploc, bsum, N);
    scan_top_kernel<<<1, 256, 0, stream>>>(bsum, boff, nbScan);
    finalize_kernel<<<nbScan, 256, 0, stream>>>(cnt, rploc, boff, rowptr, inv, N);
    fill_kernel<<<(E + 255) / 256, 256, 0, stream>>>(edge_index, edge_type, cursor_pad, rowptr, packed, E);
    wcat_kernel<<<(NJ * H * H + 2 * H + 255) / 256, 256, 0, stream>>>(W1, root1, W2, root2, b1, b2,
                                                                      WTa1, WTa2, biasP);
    tobf_kernel<<<1024, 256, 0, stream>>>(node_emb, xb, (long)N * H);

    const int gx = (N + 127) / 128;
    const int gg = (N + 3) / 4;

    auto run_layer = [&](const unsigned short* xin, const unsigned short* WTa, const float* bp,
                         float* of, unsigned short* ob, int relu) {
        for (int j0 = 0; j0 < NJ; j0 += rc) {
            int j1 = (j0 + rc < NJ) ? j0 + rc : NJ;
            int fin = (j1 == NJ);
            xw_kernel<<<gx, 256, 0, stream>>>(xin, WTa, Y, N, j0, j1);
            gather_kernel<<<gg, 256, 0, stream>>>(Y, inv, rowptr, packed, bp, accf,
                                                  fin ? of : nullptr, fin ? ob : nullptr,
                                                  N, relu, j0, j1, fin);
        }
    };

    run_layer(xb, WTa1, biasP, nullptr, hb, 1);
    run_layer(hb, WTa2, biasP + H, out, nullptr, 0);
}